// Round 15
// baseline (317.044 us; speedup 1.0000x reference)
//
#include <hip/hip_runtime.h>
#include <hip/hip_bf16.h>

typedef __bf16 bf16x8 __attribute__((ext_vector_type(8)));
typedef __bf16 bf16x4 __attribute__((ext_vector_type(4)));
typedef float  f32x4  __attribute__((ext_vector_type(4)));

#define DIM    512
#define DINNER 1024
#define SEQL   256
#define NLAYER 7    // layer 7's mixer output is discarded by the reference
#define LPAD   260  // [.][l] LDS row stride: 260%32==4 -> staggered banks
#define NCH    8
#define CLEN   32

#define N4WI (NLAYER * 2048 * 512 / 4)
#define N4WX (NLAYER * 64 * 1024 / 4)
#define N4WO (NLAYER * 512 * 1024 / 4)
#define N4ALL (N4WI + N4WX + N4WO)          // 2,867,200
#define NCASTB (N4ALL / 256)                // 11200 blocks

// ---- merged: weight casts + input transpose + dblraw zero + initial ssq ----
__global__ __launch_bounds__(256) void k_castin(const float* __restrict__ Wi,
                                                const float* __restrict__ Wx,
                                                const float* __restrict__ Wo,
                                                const float* __restrict__ x,
                                                __hip_bfloat16* __restrict__ wib,
                                                __hip_bfloat16* __restrict__ wxb,
                                                __hip_bfloat16* __restrict__ wob,
                                                float* __restrict__ res,
                                                float* __restrict__ dblraw,
                                                float* __restrict__ ssq) {
  if (blockIdx.x >= NCASTB + 1024 + 32) {  // ssq region: 512 blocks, 1 token each
    int t = blockIdx.x - (NCASTB + 1024 + 32);   // t = b*256 + l
    int b = t >> 8, l = t & 255;
    const float* xb = x + ((size_t)b << 17) + l;  // x[b][d][l], d-stride 256
    int tl = threadIdx.x;
    float v0 = xb[(size_t)tl << 8];
    float v1 = xb[(size_t)(tl + 256) << 8];
    float p = v0 * v0 + v1 * v1;
#pragma unroll
    for (int m = 1; m < 64; m <<= 1) p += __shfl_xor(p, m);
    __shared__ float sred[4];
    if ((tl & 63) == 0) sred[tl >> 6] = p;
    __syncthreads();
    if (tl == 0) ssq[t] = (sred[0] + sred[1]) + (sred[2] + sred[3]);
    return;
  }
  if (blockIdx.x >= NCASTB + 1024) {  // zero dblraw[512][64]: 8192 float4, 32 blocks
    int i = (blockIdx.x - NCASTB - 1024) * 256 + threadIdx.x;
    reinterpret_cast<float4*>(dblraw)[i] = float4{0.f, 0.f, 0.f, 0.f};
    return;
  }
  if (blockIdx.x >= NCASTB) {   // transpose region: 1024 blocks
    int idx = (blockIdx.x - NCASTB) * 256 + threadIdx.x;   // B*L*DIM = 262144
    int d = idx & (DIM - 1), l = (idx >> 9) & (SEQL - 1), b = idx >> 17;
    res[idx] = x[((size_t)((b << 9) + d) << 8) + l];
    return;
  }
  int i = blockIdx.x * 256 + threadIdx.x;
  const float* src; __hip_bfloat16* dst; int j;
  if (i < N4WI)             { src = Wi; dst = wib; j = i; }
  else if (i < N4WI + N4WX) { src = Wx; dst = wxb; j = i - N4WI; }
  else                      { src = Wo; dst = wob; j = i - N4WI - N4WX; }
  float4 v = reinterpret_cast<const float4*>(src)[j];
  struct alignas(8) B4 { __hip_bfloat16 a, b, c, d; };
  B4 o{ (__hip_bfloat16)v.x, (__hip_bfloat16)v.y, (__hip_bfloat16)v.z, (__hip_bfloat16)v.w };
  reinterpret_cast<B4*>(dst)[j] = o;
}

// ========== k1: scale-norm (ssq precomputed) + in_proj + conv + silu + x_proj ===
__global__ __launch_bounds__(1024) void k_front(const float* __restrict__ res,
                                                const float* __restrict__ ssq,
                                                const float* __restrict__ nwL,
                                                const __hip_bfloat16* __restrict__ wiL,
                                                const __hip_bfloat16* __restrict__ wxL,
                                                const float4* __restrict__ cwL,
                                                const float* __restrict__ cbL,
                                                __hip_bfloat16* __restrict__ xcb,
                                                float* __restrict__ zT,
                                                float* __restrict__ dblraw) {
  __shared__ __align__(16) char smem[79872];
  __hip_bfloat16 (*s_hn)[520] = (__hip_bfloat16(*)[520])smem;   // 49920B
  float (*s_xz)[132] = (float(*)[132])(smem + 49920);           // 25344B
  __hip_bfloat16 (*s_xcb)[72] = (__hip_bfloat16(*)[72])(smem + 75264); // 4608B
  const int tid = threadIdx.x, bid = blockIdx.x;
  const int wid = tid >> 6, lane = tid & 63;
  const int r = lane & 15, g = lane >> 4;
  const int ttile = bid >> 4, sl = bid & 15;
  const int t0 = ttile * 32, m0 = t0 - 3;
  // norm = per-row scale using precomputed ssq (no cross-lane reduce)
#pragma unroll
  for (int k = 0; k < 3; ++k) {
    int rw = wid * 3 + k;
    int grc = min(max(m0 + rw, 0), 511);
    const float* rr = res + ((size_t)grc << 9);
    float inv = rsqrtf(ssq[grc] * (1.0f / 512.0f) + 1e-5f);
#pragma unroll
    for (int j2 = 0; j2 < 8; ++j2)
      s_hn[rw][lane + (j2 << 6)] =
          (__hip_bfloat16)(rr[lane + (j2 << 6)] * inv * nwL[lane + (j2 << 6)]);
  }
  __syncthreads();
  for (int j = wid; j < 24; j += 16) {
    int mf = j >> 3, cf = j & 7;
    int gcol = (cf < 4) ? (sl * 64 + cf * 16 + r) : (1024 + sl * 64 + (cf - 4) * 16 + r);
    const bf16x8* pb = reinterpret_cast<const bf16x8*>(wiL + (size_t)gcol * 512) + g;
    f32x4 acc = {0.f, 0.f, 0.f, 0.f};
#pragma unroll
    for (int kc = 0; kc < 16; ++kc) {
      bf16x8 a = *reinterpret_cast<const bf16x8*>(&s_hn[mf * 16 + r][kc * 32 + g * 8]);
      acc = __builtin_amdgcn_mfma_f32_16x16x32_bf16(a, pb[kc * 4], acc, 0, 0, 0);
    }
    int cc = (cf < 4) ? (cf * 16 + r) : (64 + (cf - 4) * 16 + r);
#pragma unroll
    for (int jj = 0; jj < 4; ++jj) s_xz[mf * 16 + g * 4 + jj][cc] = acc[jj];
  }
  __syncthreads();
  const int t0s = t0 & 255;
#pragma unroll
  for (int k = 0; k < 2; ++k) {
    int e = tid + (k << 10);
    int lloc = e >> 6, c = e & 63;
    int gd = sl * 64 + c;
    int lseq = t0s + lloc;
    float4 wv = cwL[gd];
    float accv = cbL[gd];
    accv = fmaf(s_xz[lloc + 3][c], wv.w, accv);
    if (lseq >= 1) accv = fmaf(s_xz[lloc + 2][c], wv.z, accv);
    if (lseq >= 2) accv = fmaf(s_xz[lloc + 1][c], wv.y, accv);
    if (lseq >= 3) accv = fmaf(s_xz[lloc + 0][c], wv.x, accv);
    float sv = accv / (1.f + __expf(-accv));
    __hip_bfloat16 hb = (__hip_bfloat16)sv;
    xcb[(size_t)(t0 + lloc) * 1024 + gd] = hb;
    s_xcb[lloc][c] = hb;
  }
  __syncthreads();
  if (wid < 8) {
    int mf = wid & 1, nf = wid >> 1;
    f32x4 acc = {0.f, 0.f, 0.f, 0.f};
#pragma unroll
    for (int kc = 0; kc < 2; ++kc) {
      bf16x8 a = *reinterpret_cast<const bf16x8*>(&s_xcb[mf * 16 + r][kc * 32 + g * 8]);
      bf16x8 bb = *reinterpret_cast<const bf16x8*>(
          wxL + (size_t)(nf * 16 + r) * 1024 + sl * 64 + kc * 32 + g * 8);
      acc = __builtin_amdgcn_mfma_f32_16x16x32_bf16(a, bb, acc, 0, 0, 0);
    }
#pragma unroll
    for (int jj = 0; jj < 4; ++jj)
      atomicAdd(&dblraw[(size_t)(t0 + mf * 16 + g * 4 + jj) * 64 + nf * 16 + r], acc[jj]);
  } else {
#pragma unroll
    for (int k = 0; k < 4; ++k) {
      int e = (tid - 512) + (k << 9);
      int lloc = e & 31, c = e >> 5;
      int gd = sl * 64 + c;
      zT[(size_t)gd * 512 + t0 + lloc] = s_xz[lloc + 3][64 + c];
    }
  }
}

// ========== k2: selective scan v6 (r14 verified) + ssq zeroing ==========
__global__ __launch_bounds__(512) void k_scan(const float* __restrict__ dblraw,
                                              const float* __restrict__ WdtL,
                                              const float* __restrict__ bdtL,
                                              const __hip_bfloat16* __restrict__ xcb,
                                              const float* __restrict__ zT,
                                              const float* __restrict__ alog,
                                              const float* __restrict__ dv,
                                              __hip_bfloat16* __restrict__ y,
                                              float* __restrict__ ssqz) {
  __shared__ __align__(16) char smem[49792];
  float (*s_dt)[LPAD] = (float(*)[LPAD])(smem);           // [4][260] 4160
  float (*s_xc)[LPAD] = (float(*)[LPAD])(smem + 4160);    // 4160
  float (*s_B)[LPAD]  = (float(*)[LPAD])(smem + 8320);    // [16][260] 16640
  float (*s_C)[LPAD]  = (float(*)[LPAD])(smem + 24960);   // 16640
  float (*s_pe)[64]   = (float(*)[64]) (smem + 41600);    // [8][64] 2048
  float (*s_se)[64]   = (float(*)[64]) (smem + 43648);    // 2048
  float (*s_ys)[4]    = (float(*)[4])  (smem + 45696);    // [256][4] 4096
  const int tid = threadIdx.x, bid = blockIdx.x;
  const int cg = tid >> 6;                 // chunk 0..7
  const int tt = tid & 63;
  const int n = tt & 15, dl = tt >> 4;     // dl 0..3
  const int b = bid >> 8;
  const int d0 = (bid & 255) << 2;
  const int d = d0 + dl;
  const int bL = b * SEQL;

  // zero ssq for next layer's outproj accumulation (front already read it)
  if (bid < 2 && tid < 256) ssqz[(bid << 8) + tid] = 0.f;

  // stage B,C from dblraw cols 32..63 (4 float4 per thread, coalesced)
#pragma unroll
  for (int k = 0; k < 4; ++k) {
    int fidx = tid + (k << 9);             // 2048
    int l = fidx >> 3, q = fidx & 7;
    float4 v = *reinterpret_cast<const float4*>(dblraw + ((size_t)(bL + l) << 6) + 32 + (q << 2));
    float* dst = (q < 4) ? &s_B[(q & 3) << 2][l] : &s_C[(q & 3) << 2][l];
    dst[0] = v.x; dst[LPAD] = v.y; dst[2 * LPAD] = v.z; dst[3 * LPAD] = v.w;
  }
  // stage xc straight from xcb (bf16, L2-resident): 1 token x 4 ch per thread
  if (tid < 256) {
    bf16x4 u = *reinterpret_cast<const bf16x4*>(xcb + (size_t)(bL + tid) * 1024 + d0);
#pragma unroll
    for (int e = 0; e < 4; ++e) s_xc[e][tid] = (float)u[e];
  }
  // fused dt_proj + softplus from dblraw cols 0..31 (f32, VALU): 2 ch/thread
  {
    int tk = tid >> 1;                     // token 0..255
    int cp = (tid & 1) << 1;               // 0 or 2
    const float* drow = dblraw + ((size_t)(bL + tk) << 6);
    float xv[32];
#pragma unroll
    for (int q = 0; q < 8; ++q) {
      float4 x4 = *reinterpret_cast<const float4*>(drow + (q << 2));
      xv[q * 4 + 0] = x4.x; xv[q * 4 + 1] = x4.y;
      xv[q * 4 + 2] = x4.z; xv[q * 4 + 3] = x4.w;
    }
#pragma unroll
    for (int kk = 0; kk < 2; ++kk) {
      int ch = cp + kk;
      const float4* wr = reinterpret_cast<const float4*>(WdtL + ((size_t)(d0 + ch) << 5));
      float acc = bdtL[d0 + ch];
#pragma unroll
      for (int q = 0; q < 8; ++q) {
        float4 w = wr[q];
        acc = fmaf(xv[q * 4 + 0], w.x, acc);
        acc = fmaf(xv[q * 4 + 1], w.y, acc);
        acc = fmaf(xv[q * 4 + 2], w.z, acc);
        acc = fmaf(xv[q * 4 + 3], w.w, acc);
      }
      s_dt[ch][tk] = (acc > 20.f) ? acc : log1pf(__expf(acc));
    }
  }
  __syncthreads();

  const float An = -__expf(alog[(size_t)d * 16 + n]);
  const int lb = cg << 5;

  // pass 1
  float s = 0.f, P = 1.f;
#pragma unroll 2
  for (int l4 = 0; l4 < CLEN; l4 += 4) {
    const int l = lb + l4;
    float4 dt4 = *reinterpret_cast<const float4*>(&s_dt[dl][l]);
    float4 xc4 = *reinterpret_cast<const float4*>(&s_xc[dl][l]);
    float4 B4  = *reinterpret_cast<const float4*>(&s_B[n][l]);
    float dA;
    dA = __expf(dt4.x * An); P *= dA; s = fmaf(dA, s, dt4.x * xc4.x * B4.x);
    dA = __expf(dt4.y * An); P *= dA; s = fmaf(dA, s, dt4.y * xc4.y * B4.y);
    dA = __expf(dt4.z * An); P *= dA; s = fmaf(dA, s, dt4.z * xc4.z * B4.z);
    dA = __expf(dt4.w * An); P *= dA; s = fmaf(dA, s, dt4.w * xc4.w * B4.w);
  }
  s_pe[cg][tt] = P;
  s_se[cg][tt] = s;
  __syncthreads();

  float ss = 0.f;
  for (int c = 0; c < cg; ++c) ss = fmaf(s_pe[c][tt], ss, s_se[c][tt]);

  // pass 2: two 16-step halves, partials in registers, shfl pair-tree reduce
  float s2 = ss;
#pragma unroll
  for (int half = 0; half < 2; ++half) {
    const int base = lb + (half << 4);
    float cr[16];
#pragma unroll
    for (int l4 = 0; l4 < 16; l4 += 4) {
      const int l = base + l4;
      float4 dt4 = *reinterpret_cast<const float4*>(&s_dt[dl][l]);
      float4 xc4 = *reinterpret_cast<const float4*>(&s_xc[dl][l]);
      float4 B4  = *reinterpret_cast<const float4*>(&s_B[n][l]);
      float4 C4  = *reinterpret_cast<const float4*>(&s_C[n][l]);
      float dA;
      dA = __expf(dt4.x * An); s2 = fmaf(dA, s2, dt4.x * xc4.x * B4.x); cr[l4 + 0] = s2 * C4.x;
      dA = __expf(dt4.y * An); s2 = fmaf(dA, s2, dt4.y * xc4.y * B4.y); cr[l4 + 1] = s2 * C4.y;
      dA = __expf(dt4.z * An); s2 = fmaf(dA, s2, dt4.z * xc4.z * B4.z); cr[l4 + 2] = s2 * C4.z;
      dA = __expf(dt4.w * An); s2 = fmaf(dA, s2, dt4.w * xc4.w * B4.w); cr[l4 + 3] = s2 * C4.w;
    }
#pragma unroll
    for (int i = 0; i < 16; ++i) {
      float c = cr[i];
      c += __shfl_xor(c, 1);
      c += __shfl_xor(c, 2);
      c += __shfl_xor(c, 4);
      c += __shfl_xor(c, 8);
      cr[i] = c;
    }
    if (n == 0) {
#pragma unroll
      for (int i = 0; i < 16; ++i) s_ys[base + i][dl] = cr[i];
    }
  }
  __syncthreads();

  // epilogue: gate + store (1024 outputs, 2 per thread, coalesced)
#pragma unroll
  for (int k = 0; k < 2; ++k) {
    int idx = tid + (k << 9);
    int l = idx >> 2, dd = idx & 3;
    float sum = s_ys[l][dd];
    float xcv = s_xc[dd][l];
    float zv = zT[(size_t)(d0 + dd) * 512 + bL + l];
    float yv = (sum + dv[d0 + dd] * xcv) * (zv / (1.f + __expf(-zv)));
    y[((size_t)(bL + l) << 10) + d0 + dd] = (__hip_bfloat16)yv;
  }
}

// ===== k3: out_proj (+residual + next-layer ssq | final transposed out) =====
template <bool FINAL>
__global__ __launch_bounds__(1024) void k_outproj(const __hip_bfloat16* __restrict__ y,
                                                  const __hip_bfloat16* __restrict__ woL,
                                                  float* __restrict__ res,
                                                  float* __restrict__ out,
                                                  float* __restrict__ dblraw,
                                                  float* __restrict__ ssq) {
  __shared__ __align__(16) float s_red[16 * 1088 + 32 * 33];
  float (*s_tr)[33] = (float(*)[33])(s_red + 16 * 1088);
  const int tid = threadIdx.x, bid = blockIdx.x;
  const int wid = tid >> 6, lane = tid & 63;
  const int r = lane & 15, g = lane >> 4;
  int tile = bid >> 2, q = bid & 3;
  int row0 = (tile >> 3) * 64 + ((q >> 1) << 5);
  int col0 = (tile & 7) * 64 + ((q & 1) << 5);
  if (!FINAL && tid < 32)
    reinterpret_cast<float4*>(dblraw)[bid * 32 + tid] = float4{0.f, 0.f, 0.f, 0.f};
  {
    const bf16x8* pa0 = reinterpret_cast<const bf16x8*>(y + (size_t)(row0 + r) * 1024) + g + wid * 8;
    const bf16x8* pa1 = reinterpret_cast<const bf16x8*>(y + (size_t)(row0 + 16 + r) * 1024) + g + wid * 8;
    const bf16x8* pb0 = reinterpret_cast<const bf16x8*>(woL + (size_t)(col0 + r) * 1024) + g + wid * 8;
    const bf16x8* pb1 = reinterpret_cast<const bf16x8*>(woL + (size_t)(col0 + 16 + r) * 1024) + g + wid * 8;
    f32x4 zz = {0.f, 0.f, 0.f, 0.f};
    f32x4 acc[4] = {zz, zz, zz, zz};
#pragma unroll
    for (int kc = 0; kc < 2; ++kc) {
      bf16x8 a0 = pa0[kc * 4], a1 = pa1[kc * 4];
      bf16x8 b0 = pb0[kc * 4], b1 = pb1[kc * 4];
      acc[0] = __builtin_amdgcn_mfma_f32_16x16x32_bf16(a0, b0, acc[0], 0, 0, 0);
      acc[1] = __builtin_amdgcn_mfma_f32_16x16x32_bf16(a0, b1, acc[1], 0, 0, 0);
      acc[2] = __builtin_amdgcn_mfma_f32_16x16x32_bf16(a1, b0, acc[2], 0, 0, 0);
      acc[3] = __builtin_amdgcn_mfma_f32_16x16x32_bf16(a1, b1, acc[3], 0, 0, 0);
    }
    float* sr = s_red + wid * 1088;
#pragma unroll
    for (int e = 0; e < 4; ++e)
#pragma unroll
      for (int jj = 0; jj < 4; ++jj)
        sr[(((e >> 1) << 4) + (g << 2) + jj) * 34 + ((e & 1) << 4) + r] = acc[e][jj];
  }
  __syncthreads();
  {
    int rrow = tid >> 5, rcol = tid & 31;
    float sum = 0.f;
#pragma unroll
    for (int w = 0; w < 16; ++w) sum += s_red[w * 1088 + rrow * 34 + rcol];
    if (!FINAL) {
      float val = res[(size_t)(row0 + rrow) * 512 + col0 + rcol] + sum;
      res[(size_t)(row0 + rrow) * 512 + col0 + rcol] = val;
      // next layer's rmsnorm ssq: reduce val^2 over this block's 32 cols
      float p = val * val;
      p += __shfl_xor(p, 1); p += __shfl_xor(p, 2); p += __shfl_xor(p, 4);
      p += __shfl_xor(p, 8); p += __shfl_xor(p, 16);
      if (rcol == 0) atomicAdd(&ssq[row0 + rrow], p);
    } else {
      s_tr[rcol][rrow] = res[(size_t)(row0 + rrow) * 512 + col0 + rcol] + sum;
    }
  }
  if (FINAL) {
    __syncthreads();
    int tl = tid & 31, tc = tid >> 5;
    int b = row0 >> 8, l0 = row0 & 255;
    out[(((size_t)((b << 9) + col0 + tc)) << 8) | (l0 + tl)] = s_tr[tc][tl];
  }
}

// ---------------- launcher ----------------
extern "C" void kernel_launch(void* const* d_in, const int* in_sizes, int n_in,
                              void* d_out, int out_size, void* d_ws, size_t ws_size,
                              hipStream_t stream) {
  (void)in_sizes; (void)n_in; (void)out_size; (void)ws_size;
  const float* x    = (const float*)d_in[0];
  const float* Wi   = (const float*)d_in[1];
  const float* cw   = (const float*)d_in[2];
  const float* cb   = (const float*)d_in[3];
  const float* Wx   = (const float*)d_in[4];
  const float* Wdt  = (const float*)d_in[5];
  const float* bdt  = (const float*)d_in[6];
  const float* Alog = (const float*)d_in[7];
  const float* Dv   = (const float*)d_in[8];
  const float* Wo   = (const float*)d_in[9];
  const float* nw   = (const float*)d_in[10];

  char* ws = (char*)d_ws;
  float*          res    = (float*)(ws + 0);                  // 1 MB
  __hip_bfloat16* xcb    = (__hip_bfloat16*)(ws + 1048576);   // 1 MB
  float*          zT     = (float*)(ws + 4194304);            // 2 MB
  float*          dblraw = (float*)(ws + 6291456);            // 128 KB
  float*          ssq    = (float*)(ws + 6422528);            // 2 KB
  __hip_bfloat16* y      = (__hip_bfloat16*)(ws + 8454144);   // 1 MB
  __hip_bfloat16* wib    = (__hip_bfloat16*)(ws + 10485760);  // 14 MB
  __hip_bfloat16* wxb    = (__hip_bfloat16*)(ws + 25165824);  // 896 KB
  __hip_bfloat16* wob    = (__hip_bfloat16*)(ws + 26083328);  // 7 MB

  k_castin<<<NCASTB + 1024 + 32 + 512, 256, 0, stream>>>(Wi, Wx, Wo, x,
                                                         wib, wxb, wob,
                                                         res, dblraw, ssq);

  for (int L = 0; L < NLAYER; ++L) {
    k_front<<<256, 1024, 0, stream>>>(res, ssq, nw + L * DIM,
                                      wib + (size_t)L * 2048 * 512,
                                      wxb + (size_t)L * 64 * 1024,
                                      (const float4*)cw + (size_t)L * DINNER,
                                      cb + L * DINNER, xcb, zT, dblraw);
    k_scan<<<512, 512, 0, stream>>>(dblraw,
                                    Wdt + (size_t)L * DINNER * 32, bdt + L * DINNER,
                                    xcb, zT,
                                    Alog + (size_t)L * DINNER * 16, Dv + L * DINNER, y,
                                    ssq);
    if (L < NLAYER - 1)
      k_outproj<false><<<256, 1024, 0, stream>>>(y, wob + (size_t)L * 512 * 1024, res,
                                                 nullptr, dblraw, ssq);
    else
      k_outproj<true><<<256, 1024, 0, stream>>>(y, wob + (size_t)L * 512 * 1024, res,
                                                (float*)d_out, dblraw, ssq);
  }
}

// Round 16
// 303.138 us; speedup vs baseline: 1.0459x; 1.0459x over previous
//
#include <hip/hip_runtime.h>
#include <hip/hip_bf16.h>

typedef __bf16 bf16x8 __attribute__((ext_vector_type(8)));
typedef __bf16 bf16x4 __attribute__((ext_vector_type(4)));
typedef float  f32x4  __attribute__((ext_vector_type(4)));

#define DIM    512
#define DINNER 1024
#define SEQL   256
#define NLAYER 7    // layer 7's mixer output is discarded by the reference
#define LPAD   260  // [.][l] LDS row stride: 260%32==4 -> staggered banks
#define NCH    8
#define CLEN   32

#define N4WI (NLAYER * 2048 * 512 / 4)
#define N4WX (NLAYER * 64 * 1024 / 4)
#define N4WO (NLAYER * 512 * 1024 / 4)
#define N4ALL (N4WI + N4WX + N4WO)          // 2,867,200
#define NCASTB (N4ALL / 256)                // 11200 blocks

// ---------------- merged: weight casts + input transpose + dblraw zero ----------
__global__ __launch_bounds__(256) void k_castin(const float* __restrict__ Wi,
                                                const float* __restrict__ Wx,
                                                const float* __restrict__ Wo,
                                                const float* __restrict__ x,
                                                __hip_bfloat16* __restrict__ wib,
                                                __hip_bfloat16* __restrict__ wxb,
                                                __hip_bfloat16* __restrict__ wob,
                                                float* __restrict__ res,
                                                float* __restrict__ dblraw) {
  if (blockIdx.x >= NCASTB + 1024) {  // zero dblraw[512][64]: 8192 float4, 32 blocks
    int i = (blockIdx.x - NCASTB - 1024) * 256 + threadIdx.x;
    reinterpret_cast<float4*>(dblraw)[i] = float4{0.f, 0.f, 0.f, 0.f};
    return;
  }
  if (blockIdx.x >= NCASTB) {   // transpose region: 1024 blocks
    int idx = (blockIdx.x - NCASTB) * 256 + threadIdx.x;   // B*L*DIM = 262144
    int d = idx & (DIM - 1), l = (idx >> 9) & (SEQL - 1), b = idx >> 17;
    res[idx] = x[((size_t)((b << 9) + d) << 8) + l];
    return;
  }
  int i = blockIdx.x * 256 + threadIdx.x;
  const float* src; __hip_bfloat16* dst; int j;
  if (i < N4WI)             { src = Wi; dst = wib; j = i; }
  else if (i < N4WI + N4WX) { src = Wx; dst = wxb; j = i - N4WI; }
  else                      { src = Wo; dst = wob; j = i - N4WI - N4WX; }
  float4 v = reinterpret_cast<const float4*>(src)[j];
  struct alignas(8) B4 { __hip_bfloat16 a, b, c, d; };
  B4 o{ (__hip_bfloat16)v.x, (__hip_bfloat16)v.y, (__hip_bfloat16)v.z, (__hip_bfloat16)v.w };
  reinterpret_cast<B4*>(dst)[j] = o;
}

// ========== k1: rmsnorm + in_proj + conv + silu + partial x_proj (atomics) ======
// (round-13 verified, unchanged)
__global__ __launch_bounds__(1024) void k_front(const float* __restrict__ res,
                                                const float* __restrict__ nwL,
                                                const __hip_bfloat16* __restrict__ wiL,
                                                const __hip_bfloat16* __restrict__ wxL,
                                                const float4* __restrict__ cwL,
                                                const float* __restrict__ cbL,
                                                __hip_bfloat16* __restrict__ xcb,
                                                float* __restrict__ zT,
                                                float* __restrict__ dblraw) {
  __shared__ __align__(16) char smem[79872];
  __hip_bfloat16 (*s_hn)[520] = (__hip_bfloat16(*)[520])smem;   // 49920B
  float (*s_xz)[132] = (float(*)[132])(smem + 49920);           // 25344B
  __hip_bfloat16 (*s_xcb)[72] = (__hip_bfloat16(*)[72])(smem + 75264); // 4608B
  const int tid = threadIdx.x, bid = blockIdx.x;
  const int wid = tid >> 6, lane = tid & 63;
  const int r = lane & 15, g = lane >> 4;
  const int ttile = bid >> 4, sl = bid & 15;
  const int t0 = ttile * 32, m0 = t0 - 3;
#pragma unroll
  for (int k = 0; k < 3; ++k) {
    int rw = wid * 3 + k;
    int grc = min(max(m0 + rw, 0), 511);
    const float* rr = res + ((size_t)grc << 9);
    float v[8]; float ssum = 0.f;
#pragma unroll
    for (int j2 = 0; j2 < 8; ++j2) { v[j2] = rr[lane + (j2 << 6)]; ssum = fmaf(v[j2], v[j2], ssum); }
#pragma unroll
    for (int m = 1; m < 64; m <<= 1) ssum += __shfl_xor(ssum, m);
    float inv = rsqrtf(ssum * (1.0f / 512.0f) + 1e-5f);
#pragma unroll
    for (int j2 = 0; j2 < 8; ++j2)
      s_hn[rw][lane + (j2 << 6)] = (__hip_bfloat16)(v[j2] * inv * nwL[lane + (j2 << 6)]);
  }
  __syncthreads();
  for (int j = wid; j < 24; j += 16) {
    int mf = j >> 3, cf = j & 7;
    int gcol = (cf < 4) ? (sl * 64 + cf * 16 + r) : (1024 + sl * 64 + (cf - 4) * 16 + r);
    const bf16x8* pb = reinterpret_cast<const bf16x8*>(wiL + (size_t)gcol * 512) + g;
    f32x4 acc = {0.f, 0.f, 0.f, 0.f};
#pragma unroll
    for (int kc = 0; kc < 16; ++kc) {
      bf16x8 a = *reinterpret_cast<const bf16x8*>(&s_hn[mf * 16 + r][kc * 32 + g * 8]);
      acc = __builtin_amdgcn_mfma_f32_16x16x32_bf16(a, pb[kc * 4], acc, 0, 0, 0);
    }
    int cc = (cf < 4) ? (cf * 16 + r) : (64 + (cf - 4) * 16 + r);
#pragma unroll
    for (int jj = 0; jj < 4; ++jj) s_xz[mf * 16 + g * 4 + jj][cc] = acc[jj];
  }
  __syncthreads();
  const int t0s = t0 & 255;
#pragma unroll
  for (int k = 0; k < 2; ++k) {
    int e = tid + (k << 10);
    int lloc = e >> 6, c = e & 63;
    int gd = sl * 64 + c;
    int lseq = t0s + lloc;
    float4 wv = cwL[gd];
    float accv = cbL[gd];
    accv = fmaf(s_xz[lloc + 3][c], wv.w, accv);
    if (lseq >= 1) accv = fmaf(s_xz[lloc + 2][c], wv.z, accv);
    if (lseq >= 2) accv = fmaf(s_xz[lloc + 1][c], wv.y, accv);
    if (lseq >= 3) accv = fmaf(s_xz[lloc + 0][c], wv.x, accv);
    float sv = accv / (1.f + __expf(-accv));
    __hip_bfloat16 hb = (__hip_bfloat16)sv;
    xcb[(size_t)(t0 + lloc) * 1024 + gd] = hb;
    s_xcb[lloc][c] = hb;
  }
  __syncthreads();
  if (wid < 8) {
    int mf = wid & 1, nf = wid >> 1;
    f32x4 acc = {0.f, 0.f, 0.f, 0.f};
#pragma unroll
    for (int kc = 0; kc < 2; ++kc) {
      bf16x8 a = *reinterpret_cast<const bf16x8*>(&s_xcb[mf * 16 + r][kc * 32 + g * 8]);
      bf16x8 bb = *reinterpret_cast<const bf16x8*>(
          wxL + (size_t)(nf * 16 + r) * 1024 + sl * 64 + kc * 32 + g * 8);
      acc = __builtin_amdgcn_mfma_f32_16x16x32_bf16(a, bb, acc, 0, 0, 0);
    }
#pragma unroll
    for (int jj = 0; jj < 4; ++jj)
      atomicAdd(&dblraw[(size_t)(t0 + mf * 16 + g * 4 + jj) * 64 + nf * 16 + r], acc[jj]);
  } else {
#pragma unroll
    for (int k = 0; k < 4; ++k) {
      int e = (tid - 512) + (k << 9);
      int lloc = e & 31, c = e >> 5;
      int gd = sl * 64 + c;
      zT[(size_t)gd * 512 + t0 + lloc] = s_xz[lloc + 3][64 + c];
    }
  }
}

// ========== k2: selective scan v6 — 512 blocks x 512 thr, 4 ch/block ==========
// Same verified math (8 chunks x 32 steps, pair-tree n-reduction); partials in
// registers, s_ys[256][4] only. LDS 49.8KB -> 3 blocks/CU; grid 512 -> 2/CU
// co-resident so serial phases overlap across blocks.
__global__ __launch_bounds__(512) void k_scan(const float* __restrict__ dblraw,
                                              const float* __restrict__ WdtL,
                                              const float* __restrict__ bdtL,
                                              const __hip_bfloat16* __restrict__ xcb,
                                              const float* __restrict__ zT,
                                              const float* __restrict__ alog,
                                              const float* __restrict__ dv,
                                              __hip_bfloat16* __restrict__ y) {
  __shared__ __align__(16) char smem[49792];
  float (*s_dt)[LPAD] = (float(*)[LPAD])(smem);           // [4][260] 4160
  float (*s_xc)[LPAD] = (float(*)[LPAD])(smem + 4160);    // 4160
  float (*s_B)[LPAD]  = (float(*)[LPAD])(smem + 8320);    // [16][260] 16640
  float (*s_C)[LPAD]  = (float(*)[LPAD])(smem + 24960);   // 16640
  float (*s_pe)[64]   = (float(*)[64]) (smem + 41600);    // [8][64] 2048
  float (*s_se)[64]   = (float(*)[64]) (smem + 43648);    // 2048
  float (*s_ys)[4]    = (float(*)[4])  (smem + 45696);    // [256][4] 4096
  const int tid = threadIdx.x, bid = blockIdx.x;
  const int cg = tid >> 6;                 // chunk 0..7
  const int tt = tid & 63;
  const int n = tt & 15, dl = tt >> 4;     // dl 0..3
  const int b = bid >> 8;
  const int d0 = (bid & 255) << 2;
  const int d = d0 + dl;
  const int bL = b * SEQL;

  // stage B,C from dblraw cols 32..63 (4 float4 per thread, coalesced)
#pragma unroll
  for (int k = 0; k < 4; ++k) {
    int fidx = tid + (k << 9);             // 2048
    int l = fidx >> 3, q = fidx & 7;
    float4 v = *reinterpret_cast<const float4*>(dblraw + ((size_t)(bL + l) << 6) + 32 + (q << 2));
    float* dst = (q < 4) ? &s_B[(q & 3) << 2][l] : &s_C[(q & 3) << 2][l];
    dst[0] = v.x; dst[LPAD] = v.y; dst[2 * LPAD] = v.z; dst[3 * LPAD] = v.w;
  }
  // stage xc straight from xcb (bf16, L2-resident): 1 token x 4 ch per thread
  if (tid < 256) {
    bf16x4 u = *reinterpret_cast<const bf16x4*>(xcb + (size_t)(bL + tid) * 1024 + d0);
#pragma unroll
    for (int e = 0; e < 4; ++e) s_xc[e][tid] = (float)u[e];
  }
  // fused dt_proj + softplus from dblraw cols 0..31 (f32, VALU): 2 ch/thread
  {
    int tk = tid >> 1;                     // token 0..255
    int cp = (tid & 1) << 1;               // 0 or 2
    const float* drow = dblraw + ((size_t)(bL + tk) << 6);
    float xv[32];
#pragma unroll
    for (int q = 0; q < 8; ++q) {
      float4 x4 = *reinterpret_cast<const float4*>(drow + (q << 2));
      xv[q * 4 + 0] = x4.x; xv[q * 4 + 1] = x4.y;
      xv[q * 4 + 2] = x4.z; xv[q * 4 + 3] = x4.w;
    }
#pragma unroll
    for (int kk = 0; kk < 2; ++kk) {
      int ch = cp + kk;
      const float4* wr = reinterpret_cast<const float4*>(WdtL + ((size_t)(d0 + ch) << 5));
      float acc = bdtL[d0 + ch];
#pragma unroll
      for (int q = 0; q < 8; ++q) {
        float4 w = wr[q];
        acc = fmaf(xv[q * 4 + 0], w.x, acc);
        acc = fmaf(xv[q * 4 + 1], w.y, acc);
        acc = fmaf(xv[q * 4 + 2], w.z, acc);
        acc = fmaf(xv[q * 4 + 3], w.w, acc);
      }
      s_dt[ch][tk] = (acc > 20.f) ? acc : log1pf(__expf(acc));
    }
  }
  __syncthreads();

  const float An = -__expf(alog[(size_t)d * 16 + n]);
  const int lb = cg << 5;

  // pass 1
  float s = 0.f, P = 1.f;
#pragma unroll 2
  for (int l4 = 0; l4 < CLEN; l4 += 4) {
    const int l = lb + l4;
    float4 dt4 = *reinterpret_cast<const float4*>(&s_dt[dl][l]);
    float4 xc4 = *reinterpret_cast<const float4*>(&s_xc[dl][l]);
    float4 B4  = *reinterpret_cast<const float4*>(&s_B[n][l]);
    float dA;
    dA = __expf(dt4.x * An); P *= dA; s = fmaf(dA, s, dt4.x * xc4.x * B4.x);
    dA = __expf(dt4.y * An); P *= dA; s = fmaf(dA, s, dt4.y * xc4.y * B4.y);
    dA = __expf(dt4.z * An); P *= dA; s = fmaf(dA, s, dt4.z * xc4.z * B4.z);
    dA = __expf(dt4.w * An); P *= dA; s = fmaf(dA, s, dt4.w * xc4.w * B4.w);
  }
  s_pe[cg][tt] = P;
  s_se[cg][tt] = s;
  __syncthreads();

  // exact chunk start state (<=7 iters, wave-uniform)
  float ss = 0.f;
  for (int c = 0; c < cg; ++c) ss = fmaf(s_pe[c][tt], ss, s_se[c][tt]);

  // pass 2: two 16-step halves, partials in registers, shfl pair-tree reduce
  float s2 = ss;
#pragma unroll
  for (int half = 0; half < 2; ++half) {
    const int base = lb + (half << 4);
    float cr[16];
#pragma unroll
    for (int l4 = 0; l4 < 16; l4 += 4) {
      const int l = base + l4;
      float4 dt4 = *reinterpret_cast<const float4*>(&s_dt[dl][l]);
      float4 xc4 = *reinterpret_cast<const float4*>(&s_xc[dl][l]);
      float4 B4  = *reinterpret_cast<const float4*>(&s_B[n][l]);
      float4 C4  = *reinterpret_cast<const float4*>(&s_C[n][l]);
      float dA;
      dA = __expf(dt4.x * An); s2 = fmaf(dA, s2, dt4.x * xc4.x * B4.x); cr[l4 + 0] = s2 * C4.x;
      dA = __expf(dt4.y * An); s2 = fmaf(dA, s2, dt4.y * xc4.y * B4.y); cr[l4 + 1] = s2 * C4.y;
      dA = __expf(dt4.z * An); s2 = fmaf(dA, s2, dt4.z * xc4.z * B4.z); cr[l4 + 2] = s2 * C4.z;
      dA = __expf(dt4.w * An); s2 = fmaf(dA, s2, dt4.w * xc4.w * B4.w); cr[l4 + 3] = s2 * C4.w;
    }
#pragma unroll
    for (int i = 0; i < 16; ++i) {
      float c = cr[i];
      c += __shfl_xor(c, 1);
      c += __shfl_xor(c, 2);
      c += __shfl_xor(c, 4);
      c += __shfl_xor(c, 8);
      cr[i] = c;
    }
    if (n == 0) {
#pragma unroll
      for (int i = 0; i < 16; ++i) s_ys[base + i][dl] = cr[i];
    }
  }
  __syncthreads();

  // epilogue: gate + store (1024 outputs, 2 per thread, coalesced)
#pragma unroll
  for (int k = 0; k < 2; ++k) {
    int idx = tid + (k << 9);
    int l = idx >> 2, dd = idx & 3;
    float sum = s_ys[l][dd];
    float xcv = s_xc[dd][l];
    float zv = zT[(size_t)(d0 + dd) * 512 + bL + l];
    float yv = (sum + dv[d0 + dd] * xcv) * (zv / (1.f + __expf(-zv)));
    y[((size_t)(bL + l) << 10) + d0 + dd] = (__hip_bfloat16)yv;
  }
}

// ========== k3: out_proj (+residual | final transposed out) + dblraw zeroing ====
template <bool FINAL>
__global__ __launch_bounds__(1024) void k_outproj(const __hip_bfloat16* __restrict__ y,
                                                  const __hip_bfloat16* __restrict__ woL,
                                                  float* __restrict__ res,
                                                  float* __restrict__ out,
                                                  float* __restrict__ dblraw) {
  __shared__ __align__(16) float s_red[16 * 1088 + 32 * 33];
  float (*s_tr)[33] = (float(*)[33])(s_red + 16 * 1088);
  const int tid = threadIdx.x, bid = blockIdx.x;
  const int wid = tid >> 6, lane = tid & 63;
  const int r = lane & 15, g = lane >> 4;
  int tile = bid >> 2, q = bid & 3;
  int row0 = (tile >> 3) * 64 + ((q >> 1) << 5);
  int col0 = (tile & 7) * 64 + ((q & 1) << 5);
  if (!FINAL && tid < 32)
    reinterpret_cast<float4*>(dblraw)[bid * 32 + tid] = float4{0.f, 0.f, 0.f, 0.f};
  {
    const bf16x8* pa0 = reinterpret_cast<const bf16x8*>(y + (size_t)(row0 + r) * 1024) + g + wid * 8;
    const bf16x8* pa1 = reinterpret_cast<const bf16x8*>(y + (size_t)(row0 + 16 + r) * 1024) + g + wid * 8;
    const bf16x8* pb0 = reinterpret_cast<const bf16x8*>(woL + (size_t)(col0 + r) * 1024) + g + wid * 8;
    const bf16x8* pb1 = reinterpret_cast<const bf16x8*>(woL + (size_t)(col0 + 16 + r) * 1024) + g + wid * 8;
    f32x4 zz = {0.f, 0.f, 0.f, 0.f};
    f32x4 acc[4] = {zz, zz, zz, zz};
#pragma unroll
    for (int kc = 0; kc < 2; ++kc) {
      bf16x8 a0 = pa0[kc * 4], a1 = pa1[kc * 4];
      bf16x8 b0 = pb0[kc * 4], b1 = pb1[kc * 4];
      acc[0] = __builtin_amdgcn_mfma_f32_16x16x32_bf16(a0, b0, acc[0], 0, 0, 0);
      acc[1] = __builtin_amdgcn_mfma_f32_16x16x32_bf16(a0, b1, acc[1], 0, 0, 0);
      acc[2] = __builtin_amdgcn_mfma_f32_16x16x32_bf16(a1, b0, acc[2], 0, 0, 0);
      acc[3] = __builtin_amdgcn_mfma_f32_16x16x32_bf16(a1, b1, acc[3], 0, 0, 0);
    }
    float* sr = s_red + wid * 1088;
#pragma unroll
    for (int e = 0; e < 4; ++e)
#pragma unroll
      for (int jj = 0; jj < 4; ++jj)
        sr[(((e >> 1) << 4) + (g << 2) + jj) * 34 + ((e & 1) << 4) + r] = acc[e][jj];
  }
  __syncthreads();
  {
    int rrow = tid >> 5, rcol = tid & 31;
    float sum = 0.f;
#pragma unroll
    for (int w = 0; w < 16; ++w) sum += s_red[w * 1088 + rrow * 34 + rcol];
    if (!FINAL) {
      res[(size_t)(row0 + rrow) * 512 + col0 + rcol] += sum;
    } else {
      s_tr[rcol][rrow] = res[(size_t)(row0 + rrow) * 512 + col0 + rcol] + sum;
    }
  }
  if (FINAL) {
    __syncthreads();
    int tl = tid & 31, tc = tid >> 5;
    int b = row0 >> 8, l0 = row0 & 255;
    out[(((size_t)((b << 9) + col0 + tc)) << 8) | (l0 + tl)] = s_tr[tc][tl];
  }
}

// ---------------- launcher ----------------
extern "C" void kernel_launch(void* const* d_in, const int* in_sizes, int n_in,
                              void* d_out, int out_size, void* d_ws, size_t ws_size,
                              hipStream_t stream) {
  (void)in_sizes; (void)n_in; (void)out_size; (void)ws_size;
  const float* x    = (const float*)d_in[0];
  const float* Wi   = (const float*)d_in[1];
  const float* cw   = (const float*)d_in[2];
  const float* cb   = (const float*)d_in[3];
  const float* Wx   = (const float*)d_in[4];
  const float* Wdt  = (const float*)d_in[5];
  const float* bdt  = (const float*)d_in[6];
  const float* Alog = (const float*)d_in[7];
  const float* Dv   = (const float*)d_in[8];
  const float* Wo   = (const float*)d_in[9];
  const float* nw   = (const float*)d_in[10];

  char* ws = (char*)d_ws;
  float*          res    = (float*)(ws + 0);                  // 1 MB
  __hip_bfloat16* xcb    = (__hip_bfloat16*)(ws + 1048576);   // 1 MB
  float*          zT     = (float*)(ws + 4194304);            // 2 MB
  float*          dblraw = (float*)(ws + 6291456);            // 128 KB
  __hip_bfloat16* y      = (__hip_bfloat16*)(ws + 8454144);   // 1 MB
  __hip_bfloat16* wib    = (__hip_bfloat16*)(ws + 10485760);  // 14 MB
  __hip_bfloat16* wxb    = (__hip_bfloat16*)(ws + 25165824);  // 896 KB
  __hip_bfloat16* wob    = (__hip_bfloat16*)(ws + 26083328);  // 7 MB

  k_castin<<<NCASTB + 1024 + 32, 256, 0, stream>>>(Wi, Wx, Wo, x, wib, wxb, wob,
                                                   res, dblraw);

  for (int L = 0; L < NLAYER; ++L) {
    k_front<<<256, 1024, 0, stream>>>(res, nw + L * DIM,
                                      wib + (size_t)L * 2048 * 512,
                                      wxb + (size_t)L * 64 * 1024,
                                      (const float4*)cw + (size_t)L * DINNER,
                                      cb + L * DINNER, xcb, zT, dblraw);
    k_scan<<<512, 512, 0, stream>>>(dblraw,
                                    Wdt + (size_t)L * DINNER * 32, bdt + L * DINNER,
                                    xcb, zT,
                                    Alog + (size_t)L * DINNER * 16, Dv + L * DINNER, y);
    if (L < NLAYER - 1)
      k_outproj<false><<<256, 1024, 0, stream>>>(y, wob + (size_t)L * 512 * 1024, res,
                                                 nullptr, dblraw);
    else
      k_outproj<true><<<256, 1024, 0, stream>>>(y, wob + (size_t)L * 512 * 1024, res,
                                                (float*)d_out, dblraw);
  }
}